// Round 9
// baseline (103.863 us; speedup 1.0000x reference)
//
#include <hip/hip_runtime.h>
#include <math.h>

// N=8192, M=64, K=256, D=16
#define M_SUB 64
#define K_CODES 256
#define D_DIM 16
#define ROW_F 1024            // floats per vecs/out row
#define THRGAP 0.0078125f     // top-2 gap below this -> exact fp64 fixup
#define TILE_B 1088           // per kt-tile: 1024 B B-fragments + 64 B NC2
#define SLICE_B (16 * TILE_B) // 17408 B per m-slice

typedef __attribute__((ext_vector_type(8))) short short8;
typedef __attribute__((ext_vector_type(4))) float f32x4;

// ---- bf16 RNE split helpers (bit-identical to the verified R3-R7 path) ----
__device__ inline unsigned bfr(float x) {
    unsigned u = __builtin_bit_cast(unsigned, x);
    return (u + 0x7FFFu + ((u >> 16) & 1u)) >> 16;
}
__device__ inline float bff(unsigned h) { return __builtin_bit_cast(float, h << 16); }

// ---- DPP 16-lane-row reduce helpers (proven R3-R7) ----
template <int C> __device__ inline float dppf(float x) {
    return __builtin_bit_cast(float,
        __builtin_amdgcn_update_dpp(0, __builtin_bit_cast(int, x), C, 0xF, 0xF, true));
}
template <int C> __device__ inline int dppi(int x) {
    return __builtin_amdgcn_update_dpp(0, x, C, 0xF, 0xF, true);
}

// =============== k0: codebook -> fragment-major packed image =================
// Per m-slice: 16 kt-tiles. Tile: lane lg*16+lr's 16-B chunk at lane*16 is
// chunk lg of code kt*16+lr ([ch d0-7|ch d8-15|cl d0-7|cl d8-15]); NC2 at +1024.
__global__ __launch_bounds__(256) void pq_convert_kernel(
    const float* __restrict__ cb, char* __restrict__ pk)
{
    const int m = blockIdx.x, k = threadIdx.x;
    const float* cp = cb + ((size_t)m * K_CODES + k) * D_DIM;
    float f[16];
    #pragma unroll
    for (int q = 0; q < 4; ++q) {
        float4 t4 = ((const float4*)cp)[q];
        f[q*4+0] = t4.x; f[q*4+1] = t4.y; f[q*4+2] = t4.z; f[q*4+3] = t4.w;
    }
    float c2 = 0.f;
    #pragma unroll
    for (int d = 0; d < 16; ++d) c2 = fmaf(f[d], f[d], c2);
    short hi[16], lo[16];
    #pragma unroll
    for (int d = 0; d < 16; ++d) {
        unsigned h = bfr(f[d]);
        hi[d] = (short)h;
        lo[d] = (short)bfr(f[d] - bff(h));
    }
    char* tb = pk + (size_t)m * SLICE_B + (k >> 4) * TILE_B;
    const int lr = k & 15;
    short8 v0 = { hi[0],hi[1],hi[2],hi[3],hi[4],hi[5],hi[6],hi[7] };
    short8 v1 = { hi[8],hi[9],hi[10],hi[11],hi[12],hi[13],hi[14],hi[15] };
    short8 v2 = { lo[0],lo[1],lo[2],lo[3],lo[4],lo[5],lo[6],lo[7] };
    short8 v3 = { lo[8],lo[9],lo[10],lo[11],lo[12],lo[13],lo[14],lo[15] };
    *(short8*)(tb +   0 + lr * 16) = v0;
    *(short8*)(tb + 256 + lr * 16) = v1;
    *(short8*)(tb + 512 + lr * 16) = v2;
    *(short8*)(tb + 768 + lr * 16) = v3;
    *(float*)(tb + 1024 + lr * 4) = -c2;
}

// ===================== k1: MFMA scores + two-pass argmax =====================
// Wave-independent (no __syncthreads). Each wave: 64 rows x 1 m, as 4
// sequential 16-row tiles (only one tile's acc live -> fits 128 VGPRs).
// Score numerics + argmax/flag semantics byte-identical to the PASSING R6.
__global__ __launch_bounds__(256, 4) void pq_mfma_kernel(
    const float* __restrict__ vecs, const float* __restrict__ cb,
    float* __restrict__ out, const char* __restrict__ pk)
{
    const int tid  = threadIdx.x;
    const int w    = tid >> 6;
    const int lane = tid & 63;
    const int lr   = lane & 15;
    const int lg   = lane >> 4;
    const int wid  = blockIdx.x * 4 + w;
    const int m    = wid >> 7;          // 128 waves per m
    const int n0   = (wid & 127) * 64;  // 64 consecutive rows per wave

    __shared__ unsigned IDXW[4][16];    // packed winner k per (t,lg) group of 4 rows
    __shared__ unsigned FLGW[4][16];    // flag nibble per group

    // m is wave-uniform: uniformize the slice base into SGPRs explicitly
    // (readfirstlane is the legal VGPR->SGPR move; "+s" then compiles).
    const char* pkm_v = pk + (size_t)m * SLICE_B;
    unsigned long long upv = (unsigned long long)pkm_v;
    unsigned plo = __builtin_amdgcn_readfirstlane((unsigned)upv);
    unsigned phi = __builtin_amdgcn_readfirstlane((unsigned)(upv >> 32));
    unsigned long long up0 = ((unsigned long long)phi << 32) | plo;
    const char* pkm = (const char*)up0;

    // ---- hoist NC2: nc2v[kt] = -||c_{kt*16+lr}||^2 ----
    float nc2v[16];
    #pragma unroll
    for (int kt = 0; kt < 16; ++kt)
        nc2v[kt] = *(const float*)(pkm + kt * TILE_B + 1024 + lr * 4);

    #pragma unroll 1
    for (int t = 0; t < 4; ++t) {
        // opaque copy of the (now SGPR) B base pointer: stops LICM/CSE from
        // hoisting all 16 B-loads across tiles (would blow the reg budget)
        unsigned long long up = up0;
        asm volatile("" : "+s"(up));
        const char* pkt = (const char*)up;

        // ---- A fragments for this tile (identical conv: scale 2, bf16 hi/lo) ----
        const float* vp = vecs + (size_t)(n0 + t * 16 + lr) * ROW_F + m * D_DIM + (lg & 1) * 8;
        float4 a4 = ((const float4*)vp)[0];
        float4 b4 = ((const float4*)vp)[1];
        float f[8];
        f[0]=2.f*a4.x; f[1]=2.f*a4.y; f[2]=2.f*a4.z; f[3]=2.f*a4.w;
        f[4]=2.f*b4.x; f[5]=2.f*b4.y; f[6]=2.f*b4.z; f[7]=2.f*b4.w;
        short hi[8], lo[8];
        #pragma unroll
        for (int e = 0; e < 8; ++e) {
            unsigned h = bfr(f[e]);
            hi[e] = (short)h;
            lo[e] = (short)bfr(f[e] - bff(h));
        }
        short8 H = { hi[0],hi[1],hi[2],hi[3],hi[4],hi[5],hi[6],hi[7] };
        short8 L = { lo[0],lo[1],lo[2],lo[3],lo[4],lo[5],lo[6],lo[7] };
        const bool hiSide = (lg < 2);
        short8 A1 = hiSide ? H : L;
        short8 A2 = hiSide ? L : H;

        // ---- scores: acc[kt] = (2v)·c - ||c||^2 (C-init=-c2, MFMA(A1),MFMA(A2)) ----
        f32x4 acc[16];
        #pragma unroll
        for (int kt = 0; kt < 16; ++kt) {
            short8 B = *(const short8*)(pkt + kt * TILE_B + lane * 16);  // coalesced 1 KB
            float nv = nc2v[kt];
            f32x4 c0 = { nv, nv, nv, nv };
            c0 = __builtin_amdgcn_mfma_f32_16x16x32_bf16(A1, B, c0, 0, 0, 0);
            c0 = __builtin_amdgcn_mfma_f32_16x16x32_bf16(A2, B, c0, 0, 0, 0);
            acc[kt] = c0;
        }

        // ---- two-pass argmax (R6-verified): max tree -> DPP -> candidate mask ----
        unsigned kp[4]; unsigned rf = 0;
        #pragma unroll
        for (int p = 0; p < 4; ++p) {          // row = t*16 + lg*4 + p
            float x0 = fmaxf(fmaxf(acc[0][p],  acc[1][p]),  acc[2][p]);
            float x1 = fmaxf(fmaxf(acc[3][p],  acc[4][p]),  acc[5][p]);
            float x2 = fmaxf(fmaxf(acc[6][p],  acc[7][p]),  acc[8][p]);
            float x3 = fmaxf(fmaxf(acc[9][p],  acc[10][p]), acc[11][p]);
            float x4 = fmaxf(fmaxf(acc[12][p], acc[13][p]), acc[14][p]);
            float b  = fmaxf(fmaxf(fmaxf(x0, x1), x2), fmaxf(fmaxf(x3, x4), acc[15][p]));
            b = fmaxf(b, dppf<0xB1>(b));
            b = fmaxf(b, dppf<0x4E>(b));
            b = fmaxf(b, dppf<0x141>(b));
            b = fmaxf(b, dppf<0x140>(b));      // full 16-lane row max
            const float bthr = b - THRGAP;
            unsigned Mm = 0;
            #pragma unroll
            for (int kt = 15; kt >= 0; --kt)
                Mm = Mm + Mm + (acc[kt][p] >= bthr ? 1u : 0u);
            int cl  = __popc(Mm);
            int bkt = __ffs(Mm) - 1;
            int bkv = Mm ? (bkt * 16 + lr) : 0x7FFFFFFF;
            cl += dppi<0xB1>(cl);  bkv = min(bkv, dppi<0xB1>(bkv));
            cl += dppi<0x4E>(cl);  bkv = min(bkv, dppi<0x4E>(bkv));
            cl += dppi<0x141>(cl); bkv = min(bkv, dppi<0x141>(bkv));
            cl += dppi<0x140>(cl); bkv = min(bkv, dppi<0x140>(bkv));
            if (bkv > 255) bkv = 0;            // NaN guard (then flagged below)
            kp[p] = (unsigned)bkv;
            rf |= (cl != 1) ? (1u << p) : 0u;  // tie/near-tie -> exact fp64 pass
        }
        if (lr == 0) {
            IDXW[w][t * 4 + lg] = kp[0] | (kp[1] << 8) | (kp[2] << 16) | (kp[3] << 24);
            FLGW[w][t * 4 + lg] = rf;
        }
    }

    // ---- inline exact fp64 fixup for flagged rows (rare, wave-uniform branch) ----
    #pragma unroll 1
    for (int e = 0; e < 16; ++e) {
        unsigned rf = FLGW[w][e];              // LDS broadcast, same for all lanes
        if (rf) {
            #pragma unroll 1
            for (int p = 0; p < 4; ++p) if (rf & (1u << p)) {
                const int r = (e >> 2) * 16 + (e & 3) * 4 + p;
                const int n = n0 + r;
                const float* vrow = vecs + (size_t)n * ROW_F + m * D_DIM;
                double vd[16];
                #pragma unroll
                for (int d = 0; d < 16; ++d) vd[d] = (double)vrow[d];
                double bs = -1e300; int bi = 0;
                #pragma unroll
                for (int j = 0; j < 4; ++j) {  // lane's codes k = lane*4+j, ascending
                    int k = lane * 4 + j;
                    const float* cp = cb + ((size_t)m * K_CODES + k) * D_DIM;
                    double vc = 0.0, c2 = 0.0;
                    #pragma unroll
                    for (int d = 0; d < 16; ++d) {
                        double cd = (double)cp[d];
                        vc = fma(vd[d], cd, vc);
                        c2 = fma(cd, cd, c2);
                    }
                    double s = 2.0 * vc - c2;
                    if (s > bs) { bs = s; bi = k; }
                }
                #pragma unroll
                for (int off = 32; off; off >>= 1) {  // first-index tie-break
                    double so = __shfl_xor(bs, off, 64);
                    int    ko = __shfl_xor(bi, off, 64);
                    if (so > bs || (so == bs && ko < bi)) { bs = so; bi = ko; }
                }
                if (lane == 0) ((char*)&IDXW[w][e])[p] = (char)bi;
            }
        }
    }

    // ---- epilogue: write winning codes (bit-exact fp32 from cb) ----
    #pragma unroll
    for (int s = 0; s < 4; ++s) {
        const int r = s * 16 + (lane >> 2);     // 4 lanes per row
        unsigned e4 = IDXW[w][r >> 2];
        const int k = (int)((e4 >> ((r & 3) * 8)) & 255u);
        const float4* src = (const float4*)(cb + ((size_t)m * K_CODES + k) * D_DIM);
        float4 val = src[lane & 3];
        float4* dst = (float4*)(out + (size_t)(n0 + r) * ROW_F + m * D_DIM);
        dst[lane & 3] = val;
    }
}

extern "C" void kernel_launch(void* const* d_in, const int* in_sizes, int n_in,
                              void* d_out, int out_size, void* d_ws, size_t ws_size,
                              hipStream_t stream) {
    const float* vecs = (const float*)d_in[0];
    const float* cb   = (const float*)d_in[1];
    float* out        = (float*)d_out;
    char* pk          = (char*)d_ws;            // 64 * 17408 = 1,114,112 B

    pq_convert_kernel<<<M_SUB, 256, 0, stream>>>(cb, pk);
    pq_mfma_kernel<<<2048, 256, 0, stream>>>(vecs, cb, out, pk);
}

// Round 10
// 60.838 us; speedup vs baseline: 1.7072x; 1.7072x over previous
//
#include <hip/hip_runtime.h>
#include <math.h>

// N=8192, M=64, K=256, D=16
#define M_SUB 64
#define K_CODES 256
#define D_DIM 16
#define ROW_F 1024            // floats per vecs/out row
#define THRGAP 0.0078125f     // top-2 gap below this -> exact fp64 fixup
#define SLICE_B 17408         // 1024 B NC2 header + 16 kt-tiles x 1024 B

typedef __attribute__((ext_vector_type(8))) short short8;
typedef __attribute__((ext_vector_type(4))) float f32x4;

// ---- bf16 RNE split helpers (bit-identical to the verified R3-R9 path) ----
__device__ inline unsigned bfr(float x) {
    unsigned u = __builtin_bit_cast(unsigned, x);
    return (u + 0x7FFFu + ((u >> 16) & 1u)) >> 16;
}
__device__ inline float bff(unsigned h) { return __builtin_bit_cast(float, h << 16); }

// ---- DPP 16-lane-row reduce helpers (proven R3-R9) ----
template <int C> __device__ inline float dppf(float x) {
    return __builtin_bit_cast(float,
        __builtin_amdgcn_update_dpp(0, __builtin_bit_cast(int, x), C, 0xF, 0xF, true));
}
template <int C> __device__ inline int dppi(int x) {
    return __builtin_amdgcn_update_dpp(0, x, C, 0xF, 0xF, true);
}

// =============== k0: codebook -> fragment-major packed image =================
// Slice layout: [0,1024) NC2 floats (-||c_k||^2, k ascending);
// [1024 + kt*1024, +1024): kt-tile, lane lg*16+lr's 16-B chunk at lane*16 is
// chunk lg of code kt*16+lr ([ch d0-7|ch d8-15|cl d0-7|cl d8-15]).
__global__ __launch_bounds__(256) void pq_convert_kernel(
    const float* __restrict__ cb, char* __restrict__ pk)
{
    const int m = blockIdx.x, k = threadIdx.x;
    const float* cp = cb + ((size_t)m * K_CODES + k) * D_DIM;
    float f[16];
    #pragma unroll
    for (int q = 0; q < 4; ++q) {
        float4 t4 = ((const float4*)cp)[q];
        f[q*4+0] = t4.x; f[q*4+1] = t4.y; f[q*4+2] = t4.z; f[q*4+3] = t4.w;
    }
    float c2 = 0.f;
    #pragma unroll
    for (int d = 0; d < 16; ++d) c2 = fmaf(f[d], f[d], c2);
    short hi[16], lo[16];
    #pragma unroll
    for (int d = 0; d < 16; ++d) {
        unsigned h = bfr(f[d]);
        hi[d] = (short)h;
        lo[d] = (short)bfr(f[d] - bff(h));
    }
    char* sb = pk + (size_t)m * SLICE_B;
    *(float*)(sb + k * 4) = -c2;                    // NC2 header
    char* tb = sb + 1024 + (k >> 4) * 1024;         // this code's kt-tile
    const int lr = k & 15;
    short8 v0 = { hi[0],hi[1],hi[2],hi[3],hi[4],hi[5],hi[6],hi[7] };
    short8 v1 = { hi[8],hi[9],hi[10],hi[11],hi[12],hi[13],hi[14],hi[15] };
    short8 v2 = { lo[0],lo[1],lo[2],lo[3],lo[4],lo[5],lo[6],lo[7] };
    short8 v3 = { lo[8],lo[9],lo[10],lo[11],lo[12],lo[13],lo[14],lo[15] };
    *(short8*)(tb +   0 + lr * 16) = v0;
    *(short8*)(tb + 256 + lr * 16) = v1;
    *(short8*)(tb + 512 + lr * 16) = v2;
    *(short8*)(tb + 768 + lr * 16) = v3;
}

// ===================== k1: MFMA scores + two-pass argmax =====================
// One 16-row x 1-m tile per wave (acc[16] = 64 VGPRs live, fits 128-reg cap
// -> 4 waves/SIMD). No intra-kernel sync. Score numerics + argmax/flag
// semantics byte-identical to the PASSING R6 kernel.
__global__ __launch_bounds__(256, 4) void pq_mfma_kernel(
    const float* __restrict__ vecs, const float* __restrict__ cb,
    float* __restrict__ out, const char* __restrict__ pk)
{
    const int tid  = threadIdx.x;
    const int w    = tid >> 6;
    const int lane = tid & 63;
    const int lr   = lane & 15;
    const int lg   = lane >> 4;
    const int wid  = blockIdx.x * 4 + w;
    const int m    = wid >> 9;          // 512 waves per m
    const int n0   = (wid & 511) * 16;  // 16 consecutive rows per wave

    __shared__ unsigned IDXW[4][4];     // packed winner k per (w, lg) 4-row group
    __shared__ unsigned FLGW[4][4];     // flag nibble per group

    const char* pkm = pk + (size_t)m * SLICE_B;

    // ---- NC2 for this lane's columns: nc2v[kt] = -||c_{kt*16+lr}||^2 ----
    float nc2v[16];
    #pragma unroll
    for (int kt = 0; kt < 16; ++kt)
        nc2v[kt] = *(const float*)(pkm + (kt * 16 + lr) * 4);

    // ---- A fragment (identical conv: scale 2, bf16 hi/lo split) ----
    const float* vp = vecs + (size_t)(n0 + lr) * ROW_F + m * D_DIM + (lg & 1) * 8;
    float4 a4 = ((const float4*)vp)[0];
    float4 b4 = ((const float4*)vp)[1];
    float f[8];
    f[0]=2.f*a4.x; f[1]=2.f*a4.y; f[2]=2.f*a4.z; f[3]=2.f*a4.w;
    f[4]=2.f*b4.x; f[5]=2.f*b4.y; f[6]=2.f*b4.z; f[7]=2.f*b4.w;
    short hi[8], lo[8];
    #pragma unroll
    for (int e = 0; e < 8; ++e) {
        unsigned h = bfr(f[e]);
        hi[e] = (short)h;
        lo[e] = (short)bfr(f[e] - bff(h));
    }
    short8 H = { hi[0],hi[1],hi[2],hi[3],hi[4],hi[5],hi[6],hi[7] };
    short8 L = { lo[0],lo[1],lo[2],lo[3],lo[4],lo[5],lo[6],lo[7] };
    const bool hiSide = (lg < 2);
    short8 A1 = hiSide ? H : L;
    short8 A2 = hiSide ? L : H;

    // ---- scores: acc[kt] = (2v)·c - ||c||^2 (C-init=-c2, MFMA(A1),MFMA(A2)) ----
    f32x4 acc[16];
    #pragma unroll
    for (int kt = 0; kt < 16; ++kt) {
        short8 B = *(const short8*)(pkm + 1024 + kt * 1024 + lane * 16);  // coalesced 1 KB
        float nv = nc2v[kt];
        f32x4 c0 = { nv, nv, nv, nv };
        c0 = __builtin_amdgcn_mfma_f32_16x16x32_bf16(A1, B, c0, 0, 0, 0);
        c0 = __builtin_amdgcn_mfma_f32_16x16x32_bf16(A2, B, c0, 0, 0, 0);
        acc[kt] = c0;
    }

    // ---- two-pass argmax (R6-verified): max tree -> DPP -> candidate mask ----
    {
        unsigned kp[4]; unsigned rf = 0;
        #pragma unroll
        for (int p = 0; p < 4; ++p) {          // row = lg*4 + p
            float x0 = fmaxf(fmaxf(acc[0][p],  acc[1][p]),  acc[2][p]);
            float x1 = fmaxf(fmaxf(acc[3][p],  acc[4][p]),  acc[5][p]);
            float x2 = fmaxf(fmaxf(acc[6][p],  acc[7][p]),  acc[8][p]);
            float x3 = fmaxf(fmaxf(acc[9][p],  acc[10][p]), acc[11][p]);
            float x4 = fmaxf(fmaxf(acc[12][p], acc[13][p]), acc[14][p]);
            float b  = fmaxf(fmaxf(fmaxf(x0, x1), x2), fmaxf(fmaxf(x3, x4), acc[15][p]));
            b = fmaxf(b, dppf<0xB1>(b));
            b = fmaxf(b, dppf<0x4E>(b));
            b = fmaxf(b, dppf<0x141>(b));
            b = fmaxf(b, dppf<0x140>(b));      // full 16-lane row max
            const float bthr = b - THRGAP;
            unsigned Mm = 0;
            #pragma unroll
            for (int kt = 15; kt >= 0; --kt)
                Mm = Mm + Mm + (acc[kt][p] >= bthr ? 1u : 0u);
            int cl  = __popc(Mm);
            int bkt = __ffs(Mm) - 1;
            int bkv = Mm ? (bkt * 16 + lr) : 0x7FFFFFFF;
            cl += dppi<0xB1>(cl);  bkv = min(bkv, dppi<0xB1>(bkv));
            cl += dppi<0x4E>(cl);  bkv = min(bkv, dppi<0x4E>(bkv));
            cl += dppi<0x141>(cl); bkv = min(bkv, dppi<0x141>(bkv));
            cl += dppi<0x140>(cl); bkv = min(bkv, dppi<0x140>(bkv));
            if (bkv > 255) bkv = 0;            // NaN guard (then flagged below)
            kp[p] = (unsigned)bkv;
            rf |= (cl != 1) ? (1u << p) : 0u;  // tie/near-tie -> exact fp64 pass
        }
        if (lr == 0) {
            IDXW[w][lg] = kp[0] | (kp[1] << 8) | (kp[2] << 16) | (kp[3] << 24);
            FLGW[w][lg] = rf;
        }
    }

    // ---- inline exact fp64 fixup for flagged rows (rare, wave-uniform branch) ----
    #pragma unroll 1
    for (int e = 0; e < 4; ++e) {
        unsigned rf = FLGW[w][e];              // LDS broadcast, same for all lanes
        if (rf) {
            #pragma unroll 1
            for (int p = 0; p < 4; ++p) if (rf & (1u << p)) {
                const int n = n0 + e * 4 + p;
                const float* vrow = vecs + (size_t)n * ROW_F + m * D_DIM;
                double vd[16];
                #pragma unroll
                for (int d = 0; d < 16; ++d) vd[d] = (double)vrow[d];
                double bs = -1e300; int bi = 0;
                #pragma unroll
                for (int j = 0; j < 4; ++j) {  // lane's codes k = lane*4+j, ascending
                    int k = lane * 4 + j;
                    const float* cp = cb + ((size_t)m * K_CODES + k) * D_DIM;
                    double vc = 0.0, c2 = 0.0;
                    #pragma unroll
                    for (int d = 0; d < 16; ++d) {
                        double cd = (double)cp[d];
                        vc = fma(vd[d], cd, vc);
                        c2 = fma(cd, cd, c2);
                    }
                    double s = 2.0 * vc - c2;
                    if (s > bs) { bs = s; bi = k; }
                }
                #pragma unroll
                for (int off = 32; off; off >>= 1) {  // first-index tie-break
                    double so = __shfl_xor(bs, off, 64);
                    int    ko = __shfl_xor(bi, off, 64);
                    if (so > bs || (so == bs && ko < bi)) { bs = so; bi = ko; }
                }
                if (lane == 0) ((char*)&IDXW[w][e])[p] = (char)bi;
            }
        }
    }

    // ---- epilogue: write winning codes (bit-exact fp32 from cb) ----
    {
        const int r = lane >> 2;                // 4 lanes per row, rows 0..15
        unsigned e4 = IDXW[w][r >> 2];
        const int k = (int)((e4 >> ((r & 3) * 8)) & 255u);
        const float4* src = (const float4*)(cb + ((size_t)m * K_CODES + k) * D_DIM);
        float4 val = src[lane & 3];
        float4* dst = (float4*)(out + (size_t)(n0 + r) * ROW_F + m * D_DIM);
        dst[lane & 3] = val;
    }
}

extern "C" void kernel_launch(void* const* d_in, const int* in_sizes, int n_in,
                              void* d_out, int out_size, void* d_ws, size_t ws_size,
                              hipStream_t stream) {
    const float* vecs = (const float*)d_in[0];
    const float* cb   = (const float*)d_in[1];
    float* out        = (float*)d_out;
    char* pk          = (char*)d_ws;            // 64 * 17408 = 1,114,112 B

    pq_convert_kernel<<<M_SUB, 256, 0, stream>>>(cb, pk);
    pq_mfma_kernel<<<8192, 256, 0, stream>>>(vecs, cb, out, pk);
}